// Round 1
// baseline (42.679 us; speedup 1.0000x reference)
//
#include <hip/hip_runtime.h>

typedef __attribute__((ext_vector_type(8))) short short8;
typedef __attribute__((ext_vector_type(16))) float f32x16;
typedef __attribute__((ext_vector_type(2))) unsigned int uint2v;

#define C_INPUT 16
#define C_OUTPUT 32
#define DIM 1024
#define HW 1026
#define CH_STRIDE (HW * HW)        /* 1052676 */
#define TH 16                      /* output rows per block   */
#define TW 32                      /* output cols per block   */
#define LDS_ROWS 18                /* TH + 2 halo             */
#define LDS_W 34                   /* TW + 2 halo             */
#define ROW_BYTES (LDS_W * 32)     /* 34 px * 16ch * 2B = 1088 */
#define LDS_BYTES (LDS_ROWS * ROW_BYTES) /* 19584 B */

__device__ __forceinline__ unsigned short f2bf(float f) {
    // fp32 -> bf16 round-to-nearest-even
    unsigned int u = __builtin_bit_cast(unsigned int, f);
    u += 0x7fffu + ((u >> 16) & 1u);
    return (unsigned short)(u >> 16);
}

__global__ __launch_bounds__(256, 4)
void gck3x3_mfma_kernel(const float* __restrict__ x,
                        const float* __restrict__ kern,
                        float* __restrict__ out) {
    __shared__ __attribute__((aligned(16))) unsigned char s_x[LDS_BYTES];

    const int tid  = threadIdx.x;
    const int lane = tid & 63;
    const int wv   = tid >> 6;      // wave id 0..3
    const int n    = lane & 31;     // N index (pixel within 32-col tile) / outch for A-load
    const int hi   = lane >> 5;     // k-group: channels 8*hi .. 8*hi+7

    // XCD-aware bijective swizzle: nwg = 2048 = 8 * 256
    const int bid = blockIdx.x;
    const int swz = (bid & 7) * 256 + (bid >> 3);
    const int bh  = swz >> 5;       // 0..63
    const int bw  = swz & 31;       // 0..31
    const int h0  = bh * TH;
    const int w0  = bw * TW;

    // ---- A fragments: W[o = lane&31][c = 8*hi + j][r][s], fp32 -> bf16 ----
    short8 af[3][3];
    {
        const int o = n;
        #pragma unroll
        for (int r = 0; r < 3; ++r) {
            #pragma unroll
            for (int s = 0; s < 3; ++s) {
                short8 v;
                #pragma unroll
                for (int j = 0; j < 8; ++j) {
                    const int c = 8 * hi + j;
                    v[j] = (short)f2bf(kern[o * 144 + c * 9 + r * 3 + s]);
                }
                af[r][s] = v;
            }
        }
    }

    // ---- stage x tile -> LDS as bf16, layout [row][w][16ch], 1-bit XOR swizzle on 16B halves ----
    #pragma unroll
    for (int k = 0; k < 10; ++k) {
        const int idx = tid + k * 256;
        if (idx < 4 * LDS_ROWS * LDS_W) {            // 2448 units of 4 channels
            const int c4  = idx / (LDS_ROWS * LDS_W);
            const int rem = idx - c4 * (LDS_ROWS * LDS_W);
            const int row = rem / LDS_W;
            const int w   = rem - row * LDS_W;
            const float* src = x + (4 * c4) * CH_STRIDE + (h0 + row) * HW + (w0 + w);
            const float f0 = src[0];
            const float f1 = src[CH_STRIDE];
            const float f2 = src[2 * CH_STRIDE];
            const float f3 = src[3 * CH_STRIDE];
            const unsigned int lo  = (unsigned int)f2bf(f0) | ((unsigned int)f2bf(f1) << 16);
            const unsigned int hi2 = (unsigned int)f2bf(f2) | ((unsigned int)f2bf(f3) << 16);
            const int p   = c4 >> 1;                               // 16B half: channels 8p..8p+7
            const int s16 = (p ^ (w >> 2) ^ (w >> 3)) & 1;         // bank-conflict swizzle
            const int off = row * ROW_BYTES + w * 32 + s16 * 16 + (c4 & 1) * 8;
            uint2v t; t.x = lo; t.y = hi2;
            *(uint2v*)(s_x + off) = t;
        }
    }
    __syncthreads();

    // ---- 9 MFMAs per output row-tile: D[o][pixel] += W[o][c] * X[c][pixel] ----
    f32x16 acc[4];
    #pragma unroll
    for (int t = 0; t < 4; ++t) {
        #pragma unroll
        for (int q = 0; q < 16; ++q) acc[t][q] = 0.0f;
    }

    #pragma unroll
    for (int t = 0; t < 4; ++t) {
        const int baserow = wv * 4 + t;              // output row within tile
        #pragma unroll
        for (int r = 0; r < 3; ++r) {
            #pragma unroll
            for (int s = 0; s < 3; ++s) {
                const int w   = n + s;
                const int s16 = (hi ^ (w >> 2) ^ (w >> 3)) & 1;
                const int off = (baserow + r) * ROW_BYTES + w * 32 + s16 * 16;
                const short8 bfr = *(const short8*)(s_x + off);   // ds_read_b128
                acc[t] = __builtin_amdgcn_mfma_f32_32x32x16_bf16(af[r][s], bfr, acc[t], 0, 0, 0);
            }
        }
    }

    // ---- epilogue: C/D layout col = lane&31, row(outch) = (q&3) + 8*(q>>2) + 4*hi ----
    #pragma unroll
    for (int t = 0; t < 4; ++t) {
        const int h = h0 + wv * 4 + t;
        #pragma unroll
        for (int q = 0; q < 16; ++q) {
            const int o = (q & 3) + 8 * (q >> 2) + 4 * hi;
            out[(o << 20) + (h << 10) + (w0 + n)] = acc[t][q];
        }
    }
}

extern "C" void kernel_launch(void* const* d_in, const int* in_sizes, int n_in,
                              void* d_out, int out_size, void* d_ws, size_t ws_size,
                              hipStream_t stream) {
    (void)in_sizes; (void)n_in; (void)d_ws; (void)ws_size; (void)out_size;
    const float* x    = (const float*)d_in[0];
    const float* kern = (const float*)d_in[1];
    float*       out  = (float*)d_out;
    gck3x3_mfma_kernel<<<2048, 256, 0, stream>>>(x, kern, out);
}